// Round 5
// baseline (454.890 us; speedup 1.0000x reference)
//
#include <hip/hip_runtime.h>

// Problem constants
#define Bv 32
#define Tv 2048
#define Hv 512
#define Dv 1024

using bf16x8 = __attribute__((ext_vector_type(8))) __bf16;
using bf16x4 = __attribute__((ext_vector_type(4))) __bf16;
using f32x4  = __attribute__((ext_vector_type(4))) float;

// ---------------------------------------------------------------------------
// Kernel 1 (fused prep): one block per h row.
//  (a) We = W_attn[h, D:2D] -> bf16 MFMA B-fragment order (threads 0..127)
//  (b) hp[b][h] = hidden[b,:] . W_attn[h,0:D] + b_attn[h]   (all 256 threads)
// ---------------------------------------------------------------------------
__global__ void prep_kernel(const float* __restrict__ hidden,
                            const float* __restrict__ W,
                            const float* __restrict__ b_attn,
                            bf16x8* __restrict__ We_sw,
                            float* __restrict__ hp) {
    int h   = blockIdx.x;            // 0..511
    int tid = threadIdx.x;           // 256

    // --- (a) swizzle We row h ---
    if (tid < 128) {
        int d = tid * 8;
        const float* src = W + h * (2 * Dv) + Dv + d;
        float4 f0 = *(const float4*)src;
        float4 f1 = *(const float4*)(src + 4);
        bf16x8 o;
        o[0] = (__bf16)f0.x; o[1] = (__bf16)f0.y; o[2] = (__bf16)f0.z; o[3] = (__bf16)f0.w;
        o[4] = (__bf16)f1.x; o[5] = (__bf16)f1.y; o[6] = (__bf16)f1.z; o[7] = (__bf16)f1.w;
        int s = ((h >> 4) * 32 + (d >> 5)) * 64 + (((d >> 3) & 3) << 4) + (h & 15);
        We_sw[s] = o;
    }

    // --- (b) hid_proj ---
    float4 wh = ((const float4*)(W + h * (2 * Dv)))[tid];
    __shared__ float red[4][Bv];
    int lane = tid & 63, w = tid >> 6;
    for (int b = 0; b < Bv; ++b) {
        float4 x = ((const float4*)(hidden + b * Dv))[tid];
        float p = wh.x * x.x + wh.y * x.y + wh.z * x.z + wh.w * x.w;
#pragma unroll
        for (int m = 1; m < 64; m <<= 1) p += __shfl_xor(p, m);
        if (lane == 0) red[w][b] = p;
    }
    __syncthreads();
    if (tid < Bv)
        hp[tid * Hv + h] = red[0][tid] + red[1][tid] + red[2][tid] + red[3][tid] + b_attn[h];
}

__device__ __forceinline__ float fast_tanh(float x) {
    float xc = fminf(fmaxf(x, -9.0f), 9.0f);
    float e  = __expf(2.0f * xc);
    return 1.0f - 2.0f / (e + 1.0f);
}

// ---------------------------------------------------------------------------
// Kernel 2: scores[b,t] = sum_h v[h]*tanh( enc[b,t,:].We[h,:] + hp[b,h] )
// Grid 1024 x 512 threads: 64 rows x 512 h per block.
// REGISTER DIET for 2 blocks/CU residency: on gfx950's unified VGPR/AGPR
// file, acc[4][4] = 64 AGPR + the old double-buffered B (64 VGPR) pushed
// total to ~148 regs -> only 1 block/CU resident (occupancy 23%) -> every
// load latency exposed with 2 waves/SIMD of TLP. Fix: single B-fragment set
// (32 VGPR), issued at chunk top BEFORE the lgkm-only barrier (barrier wait
// = B latency slack), __launch_bounds__(512,4) caps at 128 regs/wave so two
// 8-wave blocks co-reside and hide each other's stalls (m114 TLP overlap).
// ---------------------------------------------------------------------------
__global__ __launch_bounds__(512, 4) void attn_main(
    const float* __restrict__ enc, const bf16x8* __restrict__ Bg,
    const float* __restrict__ hp, const float* __restrict__ vvec,
    float* __restrict__ scores)
{
    __shared__ __align__(16) __bf16 Abuf[2][64 * 72];  // 2 x 9216 B
    __shared__ float redbuf[8][64];

    const int tid   = threadIdx.x;
    const int lane  = tid & 63;
    const int w     = tid >> 6;          // wave 0..7
    const int row0  = blockIdx.x * 64;
    const int batch = row0 >> 11;

    // --- A staging map (coalesced): thread -> row = tid>>3, d segs (tid&7)*4, +32
    const int srow = tid >> 3;           // 0..63
    const int sd0  = (tid & 7) * 4;      // 0,4,..,28
    const float* gA = enc + (row0 + srow) * Dv + sd0;
    __bf16* lw0 = &Abuf[0][srow * 72 + sd0];

    // --- B fragment base: frag(j,kt) at Bg[((w*4+j)*32 + kt)*64 + lane]
    const bf16x8* Bptr = Bg + (w * 4 * 32) * 64 + lane;

    f32x4 acc[4][4];
#pragma unroll
    for (int i = 0; i < 4; ++i)
#pragma unroll
        for (int j = 0; j < 4; ++j)
            acc[i][j] = (f32x4){0.f, 0.f, 0.f, 0.f};

    // prologue: A(0) prefetch only (B loaded per-chunk, single-buffered)
    float4 f0 = *(const float4*)gA;
    float4 f1 = *(const float4*)(gA + 32);

    const int arow  = lane & 15;
    const int acol8 = (lane >> 4) * 8;

    for (int kc = 0; kc < 16; ++kc) {
        // convert + store A(kc) into buf kc&1 (conflict-free ds_write_b64 x2)
        __bf16* p = lw0 + (kc & 1) * (64 * 72);
        bf16x4 o0, o1;
        o0[0] = (__bf16)f0.x; o0[1] = (__bf16)f0.y; o0[2] = (__bf16)f0.z; o0[3] = (__bf16)f0.w;
        o1[0] = (__bf16)f1.x; o1[1] = (__bf16)f1.y; o1[2] = (__bf16)f1.z; o1[3] = (__bf16)f1.w;
        *(bf16x4*)p        = o0;
        *(bf16x4*)(p + 32) = o1;
        // issue A(kc+1) (register-destined; NOT drained at the raw barrier)
        if (kc < 15) {
            f0 = *(const float4*)(gA + (kc + 1) * 64);
            f1 = *(const float4*)(gA + (kc + 1) * 64 + 32);
        }
        // issue B(kc) loads (L2-hot We fragments); barrier wait = their slack
        bf16x8 Bc[2][4];
#pragma unroll
        for (int ktl = 0; ktl < 2; ++ktl)
#pragma unroll
            for (int j = 0; j < 4; ++j)
                Bc[ktl][j] = Bptr[(j * 32 + kc * 2 + ktl) * 64];

        // barrier WITHOUT vmcnt drain: only LDS writes need visibility
        __builtin_amdgcn_sched_barrier(0);
        asm volatile("s_waitcnt lgkmcnt(0)" ::: "memory");
        __builtin_amdgcn_s_barrier();
        __builtin_amdgcn_sched_barrier(0);

        const __bf16* rb = &Abuf[kc & 1][0];
#pragma unroll
        for (int ktl = 0; ktl < 2; ++ktl) {
            bf16x8 a0 = *(const bf16x8*)(rb + (0 * 16 + arow) * 72 + ktl * 32 + acol8);
            bf16x8 a1 = *(const bf16x8*)(rb + (1 * 16 + arow) * 72 + ktl * 32 + acol8);
            bf16x8 a2 = *(const bf16x8*)(rb + (2 * 16 + arow) * 72 + ktl * 32 + acol8);
            bf16x8 a3 = *(const bf16x8*)(rb + (3 * 16 + arow) * 72 + ktl * 32 + acol8);
            __builtin_amdgcn_s_setprio(1);
#pragma unroll
            for (int j = 0; j < 4; ++j) {
                acc[0][j] = __builtin_amdgcn_mfma_f32_16x16x32_bf16(a0, Bc[ktl][j], acc[0][j], 0, 0, 0);
                acc[1][j] = __builtin_amdgcn_mfma_f32_16x16x32_bf16(a1, Bc[ktl][j], acc[1][j], 0, 0, 0);
                acc[2][j] = __builtin_amdgcn_mfma_f32_16x16x32_bf16(a2, Bc[ktl][j], acc[2][j], 0, 0, 0);
                acc[3][j] = __builtin_amdgcn_mfma_f32_16x16x32_bf16(a3, Bc[ktl][j], acc[3][j], 0, 0, 0);
            }
            __builtin_amdgcn_s_setprio(0);
        }
    }

    // Epilogue. C/D layout: col = lane&15, row = (lane>>4)*4 + reg
    float hpv[4], vv[4];
#pragma unroll
    for (int j = 0; j < 4; ++j) {
        int n  = w * 64 + j * 16 + (lane & 15);
        hpv[j] = hp[batch * Hv + n];
        vv[j]  = vvec[n];
    }
    const int qrow = (lane >> 4) * 4;
#pragma unroll
    for (int mt = 0; mt < 4; ++mt)
#pragma unroll
        for (int r = 0; r < 4; ++r) {
            float p = 0.f;
#pragma unroll
            for (int j = 0; j < 4; ++j)
                p += vv[j] * fast_tanh(acc[mt][j][r] + hpv[j]);
            p += __shfl_xor(p, 1);
            p += __shfl_xor(p, 2);
            p += __shfl_xor(p, 4);
            p += __shfl_xor(p, 8);
            if ((lane & 15) == 0)
                redbuf[w][mt * 16 + qrow + r] = p;
        }
    __syncthreads();
    if (tid < 64) {
        float s = 0.f;
#pragma unroll
        for (int ww = 0; ww < 8; ++ww) s += redbuf[ww][tid];
        scores[row0 + tid] = s;
    }
}

// ---------------------------------------------------------------------------
// Kernel 3: softmax over T per batch row (fp32), 512 threads
// ---------------------------------------------------------------------------
__global__ void softmax_kernel(const float* __restrict__ scores, float* __restrict__ out) {
    int b   = blockIdx.x;
    int tid = threadIdx.x;               // 512
    const float* s = scores + b * Tv;
    float local[4];
    float m = -1e30f;
#pragma unroll
    for (int i = 0; i < 4; ++i) { local[i] = s[tid + i * 512]; m = fmaxf(m, local[i]); }
    __shared__ float red[8];
    int lane = tid & 63, w = tid >> 6;
#pragma unroll
    for (int x = 1; x < 64; x <<= 1) m = fmaxf(m, __shfl_xor(m, x));
    if (lane == 0) red[w] = m;
    __syncthreads();
#pragma unroll
    for (int ww = 0; ww < 8; ++ww) m = fmaxf(m, red[ww]);
    float sum = 0.f;
#pragma unroll
    for (int i = 0; i < 4; ++i) { local[i] = __expf(local[i] - m); sum += local[i]; }
#pragma unroll
    for (int x = 1; x < 64; x <<= 1) sum += __shfl_xor(sum, x);
    __syncthreads();
    if (lane == 0) red[w] = sum;
    __syncthreads();
    sum = 0.f;
#pragma unroll
    for (int ww = 0; ww < 8; ++ww) sum += red[ww];
    float inv = 1.0f / sum;
#pragma unroll
    for (int i = 0; i < 4; ++i) out[b * Tv + tid + i * 512] = local[i] * inv;
}

// ---------------------------------------------------------------------------
extern "C" void kernel_launch(void* const* d_in, const int* in_sizes, int n_in,
                              void* d_out, int out_size, void* d_ws, size_t ws_size,
                              hipStream_t stream) {
    const float* hidden = (const float*)d_in[0];   // (32, 1024)
    const float* enc    = (const float*)d_in[1];   // (32, 2048, 1024)
    const float* W      = (const float*)d_in[2];   // (512, 2048)
    const float* b_attn = (const float*)d_in[3];   // (512,)
    const float* v      = (const float*)d_in[4];   // (512,)
    float* out = (float*)d_out;                    // (32, 1, 2048) fp32

    char* ws = (char*)d_ws;
    bf16x8* We_sw = (bf16x8*)ws;                          // 1 MB
    float*  hp    = (float*)(ws + (1 << 20));             // 64 KB
    float*  sc    = (float*)(ws + (1 << 20) + (1 << 16)); // 256 KB

    prep_kernel<<<Hv, 256, 0, stream>>>(hidden, W, b_attn, We_sw, hp);
    attn_main<<<(Bv * Tv) / 64, 512, 0, stream>>>(enc, We_sw, hp, v, sc);
    softmax_kernel<<<Bv, 512, 0, stream>>>(sc, out);
}

// Round 6
// 452.220 us; speedup vs baseline: 1.0059x; 1.0059x over previous
//
#include <hip/hip_runtime.h>

// Problem constants
#define Bv 32
#define Tv 2048
#define Hv 512
#define Dv 1024

using bf16x8 = __attribute__((ext_vector_type(8))) __bf16;
using bf16x4 = __attribute__((ext_vector_type(4))) __bf16;
using f32x4  = __attribute__((ext_vector_type(4))) float;

// ---------------------------------------------------------------------------
// Kernel 1 (fused prep): one block per h row.
//  (a) We = W_attn[h, D:2D] -> bf16 in MFMA B-fragment order (threads 0..127)
//  (b) hp[b][h] = hidden[b,:] . W_attn[h,0:D] + b_attn[h]   (all 256 threads)
// ---------------------------------------------------------------------------
__global__ void prep_kernel(const float* __restrict__ hidden,
                            const float* __restrict__ W,
                            const float* __restrict__ b_attn,
                            bf16x8* __restrict__ We_sw,
                            float* __restrict__ hp) {
    int h   = blockIdx.x;            // 0..511
    int tid = threadIdx.x;           // 256

    // --- (a) swizzle We row h ---
    if (tid < 128) {
        int d = tid * 8;
        const float* src = W + h * (2 * Dv) + Dv + d;
        float4 f0 = *(const float4*)src;
        float4 f1 = *(const float4*)(src + 4);
        bf16x8 o;
        o[0] = (__bf16)f0.x; o[1] = (__bf16)f0.y; o[2] = (__bf16)f0.z; o[3] = (__bf16)f0.w;
        o[4] = (__bf16)f1.x; o[5] = (__bf16)f1.y; o[6] = (__bf16)f1.z; o[7] = (__bf16)f1.w;
        int s = ((h >> 4) * 32 + (d >> 5)) * 64 + (((d >> 3) & 3) << 4) + (h & 15);
        We_sw[s] = o;
    }

    // --- (b) hid_proj ---
    float4 wh = ((const float4*)(W + h * (2 * Dv)))[tid];
    __shared__ float red[4][Bv];
    int lane = tid & 63, w = tid >> 6;
    for (int b = 0; b < Bv; ++b) {
        float4 x = ((const float4*)(hidden + b * Dv))[tid];
        float p = wh.x * x.x + wh.y * x.y + wh.z * x.z + wh.w * x.w;
#pragma unroll
        for (int m = 1; m < 64; m <<= 1) p += __shfl_xor(p, m);
        if (lane == 0) red[w][b] = p;
    }
    __syncthreads();
    if (tid < Bv)
        hp[tid * Hv + h] = red[0][tid] + red[1][tid] + red[2][tid] + red[3][tid] + b_attn[h];
}

__device__ __forceinline__ float fast_tanh(float x) {
    float xc = fminf(fmaxf(x, -9.0f), 9.0f);
    float e  = __expf(2.0f * xc);
    return 1.0f - 2.0f / (e + 1.0f);
}

// ---------------------------------------------------------------------------
// Kernel 2: scores[b,t] = sum_h v[h]*tanh( enc[b,t,:].We[h,:] + hp[b,h] )
// Grid 1024 x 512 threads: 64 rows x 512 h per block, 2 blocks/CU.
// FUSED-STAGE structure (T3 mechanism): BK=128 (8 chunks, 4 k-steps of 32
// each). Per k-step the wave interleaves {4 B-loads (this step), 1 A-load
// (chunk k+2), 4 ds_reads, 16 MFMA, 1 ds_write (one seg of chunk k+1,
// data loaded a full chunk ago -> no vmcnt stall)}. The serial
// stage->barrier->compute phase of R0-R5 (m233: 72% of 2-phase critical
// path) is gone; per-chunk sync = lgkmcnt(0) + raw s_barrier only.
// Double-buffer invariant identical to R0-R5 (write buf[(k+1)&1] during
// chunk k). Full unroll via macro: all indices compile-time (no scratch).
// ---------------------------------------------------------------------------
__global__ __launch_bounds__(512, 4) void attn_main(
    const float* __restrict__ enc, const bf16x8* __restrict__ Bg,
    const float* __restrict__ hp, const float* __restrict__ vvec,
    float* __restrict__ scores)
{
    __shared__ __align__(16) __bf16 Abuf[2][64 * 136];  // 2 x 17408 B
    __shared__ float redbuf[8][64];

    const int tid   = threadIdx.x;
    const int lane  = tid & 63;
    const int w     = tid >> 6;          // wave 0..7
    const int row0  = blockIdx.x * 64;
    const int batch = row0 >> 11;

    // --- A staging map (coalesced): thread -> row = tid>>3, col = (tid&7)*4 + s*32
    const int srow = tid >> 3;           // 0..63
    const int sd0  = (tid & 7) * 4;      // 0,4,..,28
    const float* gA = enc + (row0 + srow) * Dv + sd0;

    // --- B fragment base: frag(j,K) at Bg[((w*4+j)*32 + K)*64 + lane], K=0..31
    const bf16x8* Bptr = Bg + (w * 4 * 32) * 64 + lane;

    const int arow  = lane & 15;
    const int acol8 = (lane >> 4) * 8;

    f32x4 acc[4][4];
#pragma unroll
    for (int i = 0; i < 4; ++i)
#pragma unroll
        for (int j = 0; j < 4; ++j)
            acc[i][j] = (f32x4){0.f, 0.f, 0.f, 0.f};

    // prologue: stage chunk 0 into buf0; start chunk-1 loads (left in flight)
    float4 fA[4], fB[4];
    {
#pragma unroll
        for (int s = 0; s < 4; ++s) fA[s] = *(const float4*)(gA + s * 32);
        __bf16* wb = &Abuf[0][srow * 136 + sd0];
#pragma unroll
        for (int s = 0; s < 4; ++s) {
            bf16x4 o;
            o[0] = (__bf16)fA[s].x; o[1] = (__bf16)fA[s].y;
            o[2] = (__bf16)fA[s].z; o[3] = (__bf16)fA[s].w;
            *(bf16x4*)(wb + s * 32) = o;
        }
#pragma unroll
        for (int s = 0; s < 4; ++s) fB[s] = *(const float4*)(gA + 128 + s * 32);
    }

    // Per chunk K (literal): read buf[K&1]; write chunk K+1 data (FW) into
    // buf[(K+1)&1] spread across k-steps; load chunk K+2 into FL.
#define CHUNK_BODY(K, FW, FL)                                                   \
    {                                                                           \
        __builtin_amdgcn_sched_barrier(0);                                      \
        asm volatile("s_waitcnt lgkmcnt(0)" ::: "memory");                      \
        __builtin_amdgcn_s_barrier();                                           \
        __builtin_amdgcn_sched_barrier(0);                                      \
        const __bf16* rb = &Abuf[(K) & 1][0];                                   \
        __bf16* wb = &Abuf[((K) + 1) & 1][srow * 136 + sd0];                    \
        _Pragma("unroll")                                                       \
        for (int s = 0; s < 4; ++s) {                                           \
            bf16x8 Bc0 = Bptr[(0 * 32 + (K) * 4 + s) * 64];                     \
            bf16x8 Bc1 = Bptr[(1 * 32 + (K) * 4 + s) * 64];                     \
            bf16x8 Bc2 = Bptr[(2 * 32 + (K) * 4 + s) * 64];                     \
            bf16x8 Bc3 = Bptr[(3 * 32 + (K) * 4 + s) * 64];                     \
            if ((K) <= 5) FL[s] = *(const float4*)(gA + ((K) + 2) * 128 + s * 32); \
            bf16x8 a0 = *(const bf16x8*)(rb + (0 * 16 + arow) * 136 + s * 32 + acol8); \
            bf16x8 a1 = *(const bf16x8*)(rb + (1 * 16 + arow) * 136 + s * 32 + acol8); \
            bf16x8 a2 = *(const bf16x8*)(rb + (2 * 16 + arow) * 136 + s * 32 + acol8); \
            bf16x8 a3 = *(const bf16x8*)(rb + (3 * 16 + arow) * 136 + s * 32 + acol8); \
            __builtin_amdgcn_s_setprio(1);                                      \
            acc[0][0] = __builtin_amdgcn_mfma_f32_16x16x32_bf16(a0, Bc0, acc[0][0], 0, 0, 0); \
            acc[1][0] = __builtin_amdgcn_mfma_f32_16x16x32_bf16(a1, Bc0, acc[1][0], 0, 0, 0); \
            acc[2][0] = __builtin_amdgcn_mfma_f32_16x16x32_bf16(a2, Bc0, acc[2][0], 0, 0, 0); \
            acc[3][0] = __builtin_amdgcn_mfma_f32_16x16x32_bf16(a3, Bc0, acc[3][0], 0, 0, 0); \
            acc[0][1] = __builtin_amdgcn_mfma_f32_16x16x32_bf16(a0, Bc1, acc[0][1], 0, 0, 0); \
            acc[1][1] = __builtin_amdgcn_mfma_f32_16x16x32_bf16(a1, Bc1, acc[1][1], 0, 0, 0); \
            acc[2][1] = __builtin_amdgcn_mfma_f32_16x16x32_bf16(a2, Bc1, acc[2][1], 0, 0, 0); \
            acc[3][1] = __builtin_amdgcn_mfma_f32_16x16x32_bf16(a3, Bc1, acc[3][1], 0, 0, 0); \
            acc[0][2] = __builtin_amdgcn_mfma_f32_16x16x32_bf16(a0, Bc2, acc[0][2], 0, 0, 0); \
            acc[1][2] = __builtin_amdgcn_mfma_f32_16x16x32_bf16(a1, Bc2, acc[1][2], 0, 0, 0); \
            acc[2][2] = __builtin_amdgcn_mfma_f32_16x16x32_bf16(a2, Bc2, acc[2][2], 0, 0, 0); \
            acc[3][2] = __builtin_amdgcn_mfma_f32_16x16x32_bf16(a3, Bc2, acc[3][2], 0, 0, 0); \
            acc[0][3] = __builtin_amdgcn_mfma_f32_16x16x32_bf16(a0, Bc3, acc[0][3], 0, 0, 0); \
            acc[1][3] = __builtin_amdgcn_mfma_f32_16x16x32_bf16(a1, Bc3, acc[1][3], 0, 0, 0); \
            acc[2][3] = __builtin_amdgcn_mfma_f32_16x16x32_bf16(a2, Bc3, acc[2][3], 0, 0, 0); \
            acc[3][3] = __builtin_amdgcn_mfma_f32_16x16x32_bf16(a3, Bc3, acc[3][3], 0, 0, 0); \
            __builtin_amdgcn_s_setprio(0);                                      \
            if ((K) <= 6) {                                                     \
                bf16x4 o;                                                       \
                o[0] = (__bf16)FW[s].x; o[1] = (__bf16)FW[s].y;                 \
                o[2] = (__bf16)FW[s].z; o[3] = (__bf16)FW[s].w;                 \
                *(bf16x4*)(wb + s * 32) = o;                                    \
            }                                                                   \
        }                                                                       \
    }

    CHUNK_BODY(0, fB, fA)
    CHUNK_BODY(1, fA, fB)
    CHUNK_BODY(2, fB, fA)
    CHUNK_BODY(3, fA, fB)
    CHUNK_BODY(4, fB, fA)
    CHUNK_BODY(5, fA, fB)
    CHUNK_BODY(6, fB, fA)
    CHUNK_BODY(7, fA, fB)
#undef CHUNK_BODY

    // Epilogue. C/D layout: col = lane&15, row = (lane>>4)*4 + reg
    float hpv[4], vv[4];
#pragma unroll
    for (int j = 0; j < 4; ++j) {
        int n  = w * 64 + j * 16 + (lane & 15);
        hpv[j] = hp[batch * Hv + n];
        vv[j]  = vvec[n];
    }
    const int qrow = (lane >> 4) * 4;
#pragma unroll
    for (int mt = 0; mt < 4; ++mt)
#pragma unroll
        for (int r = 0; r < 4; ++r) {
            float p = 0.f;
#pragma unroll
            for (int j = 0; j < 4; ++j)
                p += vv[j] * fast_tanh(acc[mt][j][r] + hpv[j]);
            p += __shfl_xor(p, 1);
            p += __shfl_xor(p, 2);
            p += __shfl_xor(p, 4);
            p += __shfl_xor(p, 8);
            if ((lane & 15) == 0)
                redbuf[w][mt * 16 + qrow + r] = p;
        }
    __syncthreads();
    if (tid < 64) {
        float s = 0.f;
#pragma unroll
        for (int ww = 0; ww < 8; ++ww) s += redbuf[ww][tid];
        scores[row0 + tid] = s;
    }
}

// ---------------------------------------------------------------------------
// Kernel 3: softmax over T per batch row (fp32), 512 threads
// ---------------------------------------------------------------------------
__global__ void softmax_kernel(const float* __restrict__ scores, float* __restrict__ out) {
    int b   = blockIdx.x;
    int tid = threadIdx.x;               // 512
    const float* s = scores + b * Tv;
    float local[4];
    float m = -1e30f;
#pragma unroll
    for (int i = 0; i < 4; ++i) { local[i] = s[tid + i * 512]; m = fmaxf(m, local[i]); }
    __shared__ float red[8];
    int lane = tid & 63, w = tid >> 6;
#pragma unroll
    for (int x = 1; x < 64; x <<= 1) m = fmaxf(m, __shfl_xor(m, x));
    if (lane == 0) red[w] = m;
    __syncthreads();
#pragma unroll
    for (int ww = 0; ww < 8; ++ww) m = fmaxf(m, red[ww]);
    float sum = 0.f;
#pragma unroll
    for (int i = 0; i < 4; ++i) { local[i] = __expf(local[i] - m); sum += local[i]; }
#pragma unroll
    for (int x = 1; x < 64; x <<= 1) sum += __shfl_xor(sum, x);
    __syncthreads();
    if (lane == 0) red[w] = sum;
    __syncthreads();
    sum = 0.f;
#pragma unroll
    for (int ww = 0; ww < 8; ++ww) sum += red[ww];
    float inv = 1.0f / sum;
#pragma unroll
    for (int i = 0; i < 4; ++i) out[b * Tv + tid + i * 512] = local[i] * inv;
}

// ---------------------------------------------------------------------------
extern "C" void kernel_launch(void* const* d_in, const int* in_sizes, int n_in,
                              void* d_out, int out_size, void* d_ws, size_t ws_size,
                              hipStream_t stream) {
    const float* hidden = (const float*)d_in[0];   // (32, 1024)
    const float* enc    = (const float*)d_in[1];   // (32, 2048, 1024)
    const float* W      = (const float*)d_in[2];   // (512, 2048)
    const float* b_attn = (const float*)d_in[3];   // (512,)
    const float* v      = (const float*)d_in[4];   // (512,)
    float* out = (float*)d_out;                    // (32, 1, 2048) fp32

    char* ws = (char*)d_ws;
    bf16x8* We_sw = (bf16x8*)ws;                          // 1 MB
    float*  hp    = (float*)(ws + (1 << 20));             // 64 KB
    float*  sc    = (float*)(ws + (1 << 20) + (1 << 16)); // 256 KB

    prep_kernel<<<Hv, 256, 0, stream>>>(hidden, W, b_attn, We_sw, hp);
    attn_main<<<(Bv * Tv) / 64, 512, 0, stream>>>(enc, We_sw, hp, v, sc);
    softmax_kernel<<<Bv, 512, 0, stream>>>(sc, out);
}